// Round 5
// baseline (88.538 us; speedup 1.0000x reference)
//
#include <hip/hip_runtime.h>
#include <hip/hip_bf16.h>
#include <math.h>

// Problem constants (match reference)
#define NB 1024            // batch
#define MP 8               // stripes per sample
#define DF 128             // feature dim
#define NV (NB*MP)         // 8192 local vectors
#define EPSR 1e-12f
#define MARGIN_ 0.3f

// Degree-4 Chebyshev interpolant of g(y) = tanh(sqrt(y)/2)/sqrt(y) on [0,4].
// tanh(sqrt(y)/2) = sqrt(y) * g(y). Max |err| ~1e-4 over [0,4].
#define GC0  0.4999965f
#define GC1 -0.0416276f
#define GC2  0.0040808f
#define GC3 -0.00035138f
#define GC4  0.00001765f

typedef __bf16 bf16x8 __attribute__((ext_vector_type(8)));
typedef float  f32x4  __attribute__((ext_vector_type(4)));

// ---------------------------------------------------------------------------
// Kernel 1: L2-normalize each of the 8192 local vectors -> bf16 for MFMA.
// NOTE: the reference's sq (post-eps-normalize squared norm) is 1.0f +- 1ulp
// in fp32 for these inputs (||x|| ~ 11, eps=1e-12 << fp32 ulp), so the
// epilogue uses d2 = 2 - 2*dot exactly; sq is not materialized.
// Block 0 also initializes the ap/an mining accumulators (uint-ordered
// floats: an=+inf pattern, ap=0).
// ---------------------------------------------------------------------------
__global__ __launch_bounds__(256) void norm_kernel(const float* __restrict__ x,
                                                   unsigned short* __restrict__ xnb,
                                                   unsigned* __restrict__ ap_max,
                                                   unsigned* __restrict__ an_min) {
    if (blockIdx.x == 0) {
        for (int i = threadIdx.x; i < NB; i += 256) {
            ap_max[i] = 0u;            // floats >= 0: uint order == float order
            an_min[i] = 0x7F800000u;   // +inf
        }
    }
    const int wave = threadIdx.x >> 6;
    const int lane = threadIdx.x & 63;
    const int v = blockIdx.x * 4 + wave;      // vector index [0, 8192)
    const float e0 = x[v * DF + lane];
    const float e1 = x[v * DF + 64 + lane];
    float s = e0 * e0 + e1 * e1;
    #pragma unroll
    for (int off = 32; off > 0; off >>= 1) s += __shfl_xor(s, off);
    const float inv = 1.0f / (sqrtf(s) + EPSR);
    const __hip_bfloat16 b0 = __float2bfloat16(e0 * inv);
    const __hip_bfloat16 b1 = __float2bfloat16(e1 * inv);
    xnb[v * DF + lane]      = *(const unsigned short*)&b0;
    xnb[v * DF + 64 + lane] = *(const unsigned short*)&b1;
}

// ---------------------------------------------------------------------------
// Kernel 2: MFMA Gram + fused tanh-dist + 8x8 DTW DP + fused hard mining.
// Upper-triangular 16x16-sample tiles (DTW dist is symmetric). Block = 256
// threads (4 waves); K=128 staged in LDS as bf16; wave (wr,wc) computes a
// 64x64 Gram quadrant via 4x4 mfma_f32_16x16x32_bf16. Gram round-trips
// through LDS in per-pair col-major 64-float blocks (one ds_write_b128 per
// acc f32x4), XOR-swizzled -> conflict-free. Epilogue: td = sqrt(d2)*poly4(d2)
// fused into the gather; DP is pure min+add. The resulting per-pair DTW
// distance is reduced in-wave (shfl) and folded into per-row ap/an via
// uint atomics -- the NxN dist matrix is never materialized.
// ---------------------------------------------------------------------------
__global__ __launch_bounds__(256) void dist_kernel(const unsigned short* __restrict__ xnb,
                                                   const int* __restrict__ labels,
                                                   unsigned* __restrict__ ap_max,
                                                   unsigned* __restrict__ an_min) {
    __shared__ alignas(16) unsigned char smem[65536];   // 64 KB (union)
    unsigned short* As = (unsigned short*)smem;          // 128 x 128 bf16 (32 KB)
    unsigned short* Bs = (unsigned short*)(smem + 32768);
    float* E = (float*)smem;                             // 256 pair-blocks x 64 fp32

    // triangular decode: blockIdx.x -> (bx <= by)
    const int idx = (int)blockIdx.x;
    float fsq = sqrtf(8.0f * (float)idx + 1.0f);
    int by = (int)((fsq - 1.0f) * 0.5f);
    while ((by + 1) * (by + 2) / 2 <= idx) ++by;
    while (by * (by + 1) / 2 > idx) --by;
    const int bx = idx - by * (by + 1) / 2;

    const int t    = threadIdx.x;
    const int wave = t >> 6;
    const int lane = t & 63;
    const int wr   = wave >> 1;
    const int wc   = wave & 1;
    const int aBase = bx * 16;    // sample indices
    const int bBase = by * 16;

    // ---- stage A and B tiles: 128 rows x 16 chunks (16 B) each side
    #pragma unroll
    for (int i = 0; i < 8; ++i) {
        const int ldi = t + i * 256;           // [0, 2048)
        const int row = ldi >> 4;              // vector within tile [0,128)
        const int ch  = ldi & 15;              // 16B chunk within row
        const int p   = ch ^ (row & 15);       // swizzled chunk position
        const uint4 va = *(const uint4*)&xnb[(aBase * MP + row) * DF + ch * 8];
        const uint4 vb = *(const uint4*)&xnb[(bBase * MP + row) * DF + ch * 8];
        *(uint4*)&As[row * DF + p * 8] = va;
        *(uint4*)&Bs[row * DF + p * 8] = vb;
    }
    __syncthreads();

    // ---- MFMA phase: 4 k-steps x 16 tiles per wave
    f32x4 acc[4][4];
    #pragma unroll
    for (int tr = 0; tr < 4; ++tr)
        #pragma unroll
        for (int tc = 0; tc < 4; ++tc) acc[tr][tc] = (f32x4){0.f, 0.f, 0.f, 0.f};

    const int fr = lane & 15;        // fragment row within 16
    const int fq = lane >> 4;        // quad
    #pragma unroll
    for (int ks = 0; ks < 4; ++ks) {
        bf16x8 af[4], bfr[4];
        const int ch = ks * 4 + fq;
        #pragma unroll
        for (int tr = 0; tr < 4; ++tr) {
            const int va = wr * 64 + tr * 16 + fr;
            af[tr] = *(const bf16x8*)&As[va * DF + (ch ^ fr) * 8];
        }
        #pragma unroll
        for (int tc = 0; tc < 4; ++tc) {
            const int vb = wc * 64 + tc * 16 + fr;
            bfr[tc] = *(const bf16x8*)&Bs[vb * DF + (ch ^ fr) * 8];
        }
        #pragma unroll
        for (int tr = 0; tr < 4; ++tr)
            #pragma unroll
            for (int tc = 0; tc < 4; ++tc)
                acc[tr][tc] = __builtin_amdgcn_mfma_f32_16x16x32_bf16(
                    af[tr], bfr[tc], acc[tr][tc], 0, 0, 0);
    }
    __syncthreads();   // staging reads done before E overwrites

    // ---- scatter acc -> per-pair col-major blocks, one b128 per (tr,tc)
    #pragma unroll
    for (int tr = 0; tr < 4; ++tr) {
        const int r0 = wr * 64 + tr * 16 + fq * 4;
        const int aL = r0 >> 3;
        const int cqr = fq & 1;                 // i>>2 within 8-row block
        #pragma unroll
        for (int tc = 0; tc < 4; ++tc) {
            const int c  = wc * 64 + tc * 16 + fr;
            const int bL = c >> 3, j = c & 7;
            const int cq = (j << 1) | cqr;      // chunk = col j, row-half
            const int p  = (cq ^ bL) & 15;      // swizzled chunk position
            *(f32x4*)&E[(((aL << 4) + bL) << 6) + (p << 2)] = acc[tr][tc];
        }
    }
    __syncthreads();

    // ---- gather (conflict-free) fused with tanh-dist conversion
    float g8[8][8];   // g8[i][j] = tanh(sqrt(d2_ij)/2)
    {
        const int bL = t & 15;
        #pragma unroll
        for (int cq = 0; cq < 16; ++cq) {
            const int p = (cq ^ bL) & 15;
            const f32x4 v = *(const f32x4*)&E[(t << 6) + (p << 2)];
            const int j = cq >> 1, ib = (cq & 1) * 4;
            #pragma unroll
            for (int g = 0; g < 4; ++g) {
                const float d2 = fmaxf(fmaf(-2.0f, v[g], 2.0f), EPSR);
                const float d  = __builtin_amdgcn_sqrtf(d2);
                const float pg = fmaf(fmaf(fmaf(fmaf(GC4, d2, GC3), d2, GC2),
                                           d2, GC1), d2, GC0);
                g8[ib + g][j] = d * pg;
            }
        }
    }

    // ---- DTW DP: pure min+add over precomputed g8
    float rowv[8];
    {
        float c = 0.0f;
        #pragma unroll
        for (int j = 0; j < 8; ++j) { c += g8[0][j]; rowv[j] = c; }
    }
    #pragma unroll
    for (int i = 1; i < 8; ++i) {
        float carry = INFINITY;
        #pragma unroll
        for (int j = 0; j < 8; ++j) {
            const float v = fminf(carry, rowv[j]) + g8[i][j];
            rowv[j] = v;
            carry = v;
        }
    }
    const float d = rowv[7];        // DTW dist for pair (aG, bG)

    // ---- fused hard mining: in-wave reduce + per-row uint atomics
    const int aG = aBase + (t >> 4);
    const int bG = bBase + (t & 15);
    const bool pos = (labels[aG] == labels[bG]);

    // row direction: reduce over the 16 bL lanes of each aL group
    float an_v = pos ? INFINITY : d;
    float ap_v = pos ? d : 0.0f;
    #pragma unroll
    for (int off = 1; off <= 8; off <<= 1) {
        an_v = fminf(an_v, __shfl_xor(an_v, off));
        ap_v = fmaxf(ap_v, __shfl_xor(ap_v, off));
    }
    if ((t & 15) == 0) {
        atomicMin(&an_min[aG], __float_as_uint(an_v));
        if (ap_v > 0.0f) atomicMax(&ap_max[aG], __float_as_uint(ap_v));
    }

    // column direction (mirror rows), only for off-diagonal tiles
    if (bx != by) {
        float an_m = pos ? INFINITY : d;
        float ap_m = pos ? d : 0.0f;
        an_m = fminf(an_m, __shfl_xor(an_m, 16));
        an_m = fminf(an_m, __shfl_xor(an_m, 32));
        ap_m = fmaxf(ap_m, __shfl_xor(ap_m, 16));
        ap_m = fmaxf(ap_m, __shfl_xor(ap_m, 32));
        if (lane < 16) {
            const int bG2 = bBase + lane;
            atomicMin(&an_min[bG2], __float_as_uint(an_m));
            if (ap_m > 0.0f) atomicMax(&ap_max[bG2], __float_as_uint(ap_m));
        }
    }
}

// ---------------------------------------------------------------------------
// Kernel 3: final loss = mean(relu(ap - an + margin)) over 1024 rows.
// ---------------------------------------------------------------------------
__global__ __launch_bounds__(256) void loss_kernel(const unsigned* __restrict__ ap_max,
                                                   const unsigned* __restrict__ an_min,
                                                   float* __restrict__ out) {
    __shared__ float buf[4];
    const int wave = threadIdx.x >> 6;
    const int lane = threadIdx.x & 63;
    float s = 0.0f;
    for (int i = threadIdx.x; i < NB; i += 256) {
        const float ap = __uint_as_float(ap_max[i]);
        const float an = __uint_as_float(an_min[i]);
        s += fmaxf(ap - an + MARGIN_, 0.0f);
    }
    #pragma unroll
    for (int off = 32; off > 0; off >>= 1) s += __shfl_xor(s, off);
    if (lane == 0) buf[wave] = s;
    __syncthreads();
    if (threadIdx.x == 0) {
        out[0] = (buf[0] + buf[1] + buf[2] + buf[3]) * (1.0f / (float)NB);
    }
}

// ---------------------------------------------------------------------------
// Workspace layout:
//   xnb     [8192*128] ushort   (2 MB)
//   ap_max  [1024]     uint
//   an_min  [1024]     uint
// ---------------------------------------------------------------------------
extern "C" void kernel_launch(void* const* d_in, const int* in_sizes, int n_in,
                              void* d_out, int out_size, void* d_ws, size_t ws_size,
                              hipStream_t stream) {
    const float* x      = (const float*)d_in[0];
    const int*   labels = (const int*)d_in[1];
    float* out = (float*)d_out;

    unsigned short* xnb = (unsigned short*)d_ws;
    unsigned* ap_max = (unsigned*)(xnb + (size_t)NV * DF);
    unsigned* an_min = ap_max + NB;

    const int ntiles = (NB / 16) * (NB / 16 + 1) / 2;   // 2080

    norm_kernel<<<NV / 4, 256, 0, stream>>>(x, xnb, ap_max, an_min);
    dist_kernel<<<ntiles, 256, 0, stream>>>(xnb, labels, ap_max, an_min);
    loss_kernel<<<1, 256, 0, stream>>>(ap_max, an_min, out);
}

// Round 7
// 86.713 us; speedup vs baseline: 1.0210x; 1.0210x over previous
//
#include <hip/hip_runtime.h>
#include <hip/hip_bf16.h>
#include <math.h>

// Problem constants (match reference)
#define NB 1024            // batch
#define MP 8               // stripes per sample
#define DF 128             // feature dim
#define NV (NB*MP)         // 8192 local vectors
#define EPSR 1e-12f
#define MARGIN_ 0.3f

// Degree-4 Chebyshev interpolant of g(y) = tanh(sqrt(y)/2)/sqrt(y) on [0,4].
// tanh(sqrt(y)/2) = sqrt(y) * g(y). Max |err| ~1e-4 over [0,4].
#define GC0  0.4999965f
#define GC1 -0.0416276f
#define GC2  0.0040808f
#define GC3 -0.00035138f
#define GC4  0.00001765f

typedef __bf16    bf16x8 __attribute__((ext_vector_type(8)));
typedef float     f32x4  __attribute__((ext_vector_type(4)));
typedef _Float16  f16x4  __attribute__((ext_vector_type(4)));
typedef _Float16  f16x8  __attribute__((ext_vector_type(8)));

// ---------------------------------------------------------------------------
// Kernel 1: L2-normalize each of the 8192 local vectors -> bf16 for MFMA.
// sq (post-eps-normalize squared norm) is 1.0f +- 1ulp for these inputs, so
// the epilogue uses d2 = 2 - 2*dot; sq is not materialized. Block 0 also
// initializes the ap/an mining accumulators (uint-ordered floats).
// ---------------------------------------------------------------------------
__global__ __launch_bounds__(256) void norm_kernel(const float* __restrict__ x,
                                                   unsigned short* __restrict__ xnb,
                                                   unsigned* __restrict__ ap_max,
                                                   unsigned* __restrict__ an_min) {
    if (blockIdx.x == 0) {
        for (int i = threadIdx.x; i < NB; i += 256) {
            ap_max[i] = 0u;            // floats >= 0: uint order == float order
            an_min[i] = 0x7F800000u;   // +inf
        }
    }
    const int wave = threadIdx.x >> 6;
    const int lane = threadIdx.x & 63;
    const int v = blockIdx.x * 4 + wave;      // vector index [0, 8192)
    const float e0 = x[v * DF + lane];
    const float e1 = x[v * DF + 64 + lane];
    float s = e0 * e0 + e1 * e1;
    #pragma unroll
    for (int off = 32; off > 0; off >>= 1) s += __shfl_xor(s, off);
    const float inv = 1.0f / (sqrtf(s) + EPSR);
    const __hip_bfloat16 b0 = __float2bfloat16(e0 * inv);
    const __hip_bfloat16 b1 = __float2bfloat16(e1 * inv);
    xnb[v * DF + lane]      = *(const unsigned short*)&b0;
    xnb[v * DF + 64 + lane] = *(const unsigned short*)&b1;
}

// ---------------------------------------------------------------------------
// Kernel 2: MFMA Gram + fused tanh-dist + 8x8 DTW DP + fused hard mining.
// Upper-triangular 16x16-sample tiles. 32 KB LDS total (5 blocks/CU):
//   - staging: K=64 bf16 chunks, 2 x 16 KB (A/B), two K-iterations
//   - E overlay: td values as f16, 256 pairs x 64 f16 = 32 KB
// Conversion td = sqrt(d2)*poly4(d2) is applied to the MFMA accumulators in
// registers, cast to f16, round-tripped through LDS into per-pair col-major
// blocks (8 f16 per col = one b128 gather per col), then the per-pair DTW DP
// and hard mining (shfl reduce + uint atomics) run. The NxN dist matrix is
// never materialized.
// ---------------------------------------------------------------------------
__global__ __launch_bounds__(256) void dist_kernel(const unsigned short* __restrict__ xnb,
                                                   const int* __restrict__ labels,
                                                   unsigned* __restrict__ ap_max,
                                                   unsigned* __restrict__ an_min) {
    __shared__ alignas(16) unsigned char smem[32768];    // 32 KB union
    unsigned short* As = (unsigned short*)smem;           // 128 rows x 64 bf16 (16 KB)
    unsigned short* Bs = (unsigned short*)(smem + 16384);
    unsigned short* E  = (unsigned short*)smem;           // 256 pairs x 64 f16 (32 KB)

    // triangular decode: blockIdx.x -> (bx <= by)
    const int idx = (int)blockIdx.x;
    float fsq = sqrtf(8.0f * (float)idx + 1.0f);
    int by = (int)((fsq - 1.0f) * 0.5f);
    while ((by + 1) * (by + 2) / 2 <= idx) ++by;
    while (by * (by + 1) / 2 > idx) --by;
    const int bx = idx - by * (by + 1) / 2;

    const int t    = threadIdx.x;
    const int wave = t >> 6;
    const int lane = t & 63;
    const int wr   = wave >> 1;
    const int wc   = wave & 1;
    const int aBase = bx * 16;    // sample indices
    const int bBase = by * 16;

    const int fr = lane & 15;        // fragment row within 16
    const int fq = lane >> 4;        // quad

    f32x4 acc[4][4];
    #pragma unroll
    for (int tr = 0; tr < 4; ++tr)
        #pragma unroll
        for (int tc = 0; tc < 4; ++tc) acc[tr][tc] = (f32x4){0.f, 0.f, 0.f, 0.f};

    // ---- two K=64 chunks: stage -> MFMA
    #pragma unroll
    for (int kci = 0; kci < 2; ++kci) {
        const int kc = kci * 64;
        if (kci) __syncthreads();    // previous chunk's reads done before overwrite
        #pragma unroll
        for (int i = 0; i < 8; ++i) {
            const int ldi  = t + i * 256;          // [0, 2048)
            const int side = ldi >> 10;            // 0=A (i<4), 1=B
            const int r    = (ldi >> 3) & 127;     // vector within tile
            const int ch   = ldi & 7;              // 16B chunk within 64-k row
            const int gv   = (side ? bBase : aBase) * MP + r;
            const uint4 v  = *(const uint4*)&xnb[gv * DF + kc + ch * 8];
            unsigned short* dst = side ? Bs : As;
            *(uint4*)&dst[r * 64 + ((ch ^ (r & 7)) * 8)] = v;
        }
        __syncthreads();

        #pragma unroll
        for (int ksl = 0; ksl < 2; ++ksl) {
            bf16x8 af[4], bfr[4];
            const int ch = ksl * 4 + fq;
            #pragma unroll
            for (int tr = 0; tr < 4; ++tr) {
                const int va = wr * 64 + tr * 16 + fr;
                af[tr] = *(const bf16x8*)&As[va * 64 + ((ch ^ (fr & 7)) * 8)];
            }
            #pragma unroll
            for (int tc = 0; tc < 4; ++tc) {
                const int vb = wc * 64 + tc * 16 + fr;
                bfr[tc] = *(const bf16x8*)&Bs[vb * 64 + ((ch ^ (fr & 7)) * 8)];
            }
            #pragma unroll
            for (int tr = 0; tr < 4; ++tr)
                #pragma unroll
                for (int tc = 0; tc < 4; ++tc)
                    acc[tr][tc] = __builtin_amdgcn_mfma_f32_16x16x32_bf16(
                        af[tr], bfr[tc], acc[tr][tc], 0, 0, 0);
        }
    }
    __syncthreads();   // all staging reads done before E overwrites

    // ---- convert acc -> td (f16) in registers, scatter to per-pair blocks.
    // acc[tr][tc] = 4 rows (r0..r0+3) of one col c. Pair block p = aL*16+bL,
    // col chunk pos = j ^ (bL&7) (16 B = 8 f16 = full col), half = fq&1.
    #pragma unroll
    for (int tr = 0; tr < 4; ++tr) {
        const int r0   = wr * 64 + tr * 16 + fq * 4;
        const int aL   = r0 >> 3;
        const int half = fq & 1;              // rows i0 = half*4 within block
        #pragma unroll
        for (int tc = 0; tc < 4; ++tc) {
            const int c  = wc * 64 + tc * 16 + fr;
            const int bL = c >> 3, j = c & 7;
            f16x4 hv;
            #pragma unroll
            for (int g = 0; g < 4; ++g) {
                const float d2 = fmaxf(fmaf(-2.0f, acc[tr][tc][g], 2.0f), 0.0f);
                const float d  = __builtin_amdgcn_sqrtf(d2);
                const float pg = fmaf(fmaf(fmaf(fmaf(GC4, d2, GC3), d2, GC2),
                                           d2, GC1), d2, GC0);
                hv[g] = (_Float16)(d * pg);
            }
            const int p   = (aL << 4) + bL;
            const int pos = j ^ (bL & 7);
            *(f16x4*)&E[(p << 6) + (pos << 3) + (half << 2)] = hv;   // b64
        }
    }
    __syncthreads();

    // ---- per-thread gather: 8 cols x 8 rows of f16 (one b128 per col)
    f16x8 colv[8];
    {
        const int s = t & 7;
        #pragma unroll
        for (int j = 0; j < 8; ++j)
            colv[j] = *(const f16x8*)&E[(t << 6) + ((j ^ s) << 3)];
    }

    // ---- DTW DP: pure min+add, unpacking f16 per element
    float rowv[8];
    {
        float c = 0.0f;
        #pragma unroll
        for (int j = 0; j < 8; ++j) { c += (float)colv[j][0]; rowv[j] = c; }
    }
    #pragma unroll
    for (int i = 1; i < 8; ++i) {
        float carry = INFINITY;
        #pragma unroll
        for (int j = 0; j < 8; ++j) {
            const float v = fminf(carry, rowv[j]) + (float)colv[j][i];
            rowv[j] = v;
            carry = v;
        }
    }
    const float d = rowv[7];        // DTW dist for pair (aG, bG)

    // ---- fused hard mining: in-wave reduce + per-row uint atomics
    const int aG = aBase + (t >> 4);
    const int bG = bBase + (t & 15);
    const bool pos = (labels[aG] == labels[bG]);

    // row direction: reduce over the 16 bL lanes of each aL group
    float an_v = pos ? INFINITY : d;
    float ap_v = pos ? d : 0.0f;
    #pragma unroll
    for (int off = 1; off <= 8; off <<= 1) {
        an_v = fminf(an_v, __shfl_xor(an_v, off));
        ap_v = fmaxf(ap_v, __shfl_xor(ap_v, off));
    }
    if ((t & 15) == 0) {
        atomicMin(&an_min[aG], __float_as_uint(an_v));
        if (ap_v > 0.0f) atomicMax(&ap_max[aG], __float_as_uint(ap_v));
    }

    // column direction (mirror rows), only for off-diagonal tiles
    if (bx != by) {
        float an_m = pos ? INFINITY : d;
        float ap_m = pos ? d : 0.0f;
        an_m = fminf(an_m, __shfl_xor(an_m, 16));
        an_m = fminf(an_m, __shfl_xor(an_m, 32));
        ap_m = fmaxf(ap_m, __shfl_xor(ap_m, 16));
        ap_m = fmaxf(ap_m, __shfl_xor(ap_m, 32));
        if (lane < 16) {
            const int bG2 = bBase + lane;
            atomicMin(&an_min[bG2], __float_as_uint(an_m));
            if (ap_m > 0.0f) atomicMax(&ap_max[bG2], __float_as_uint(ap_m));
        }
    }
}

// ---------------------------------------------------------------------------
// Kernel 3: final loss = mean(relu(ap - an + margin)) over 1024 rows.
// ---------------------------------------------------------------------------
__global__ __launch_bounds__(256) void loss_kernel(const unsigned* __restrict__ ap_max,
                                                   const unsigned* __restrict__ an_min,
                                                   float* __restrict__ out) {
    __shared__ float buf[4];
    const int wave = threadIdx.x >> 6;
    const int lane = threadIdx.x & 63;
    float s = 0.0f;
    for (int i = threadIdx.x; i < NB; i += 256) {
        const float ap = __uint_as_float(ap_max[i]);
        const float an = __uint_as_float(an_min[i]);
        s += fmaxf(ap - an + MARGIN_, 0.0f);
    }
    #pragma unroll
    for (int off = 32; off > 0; off >>= 1) s += __shfl_xor(s, off);
    if (lane == 0) buf[wave] = s;
    __syncthreads();
    if (threadIdx.x == 0) {
        out[0] = (buf[0] + buf[1] + buf[2] + buf[3]) * (1.0f / (float)NB);
    }
}

// ---------------------------------------------------------------------------
// Workspace layout:
//   xnb     [8192*128] ushort   (2 MB)
//   ap_max  [1024]     uint
//   an_min  [1024]     uint
// ---------------------------------------------------------------------------
extern "C" void kernel_launch(void* const* d_in, const int* in_sizes, int n_in,
                              void* d_out, int out_size, void* d_ws, size_t ws_size,
                              hipStream_t stream) {
    const float* x      = (const float*)d_in[0];
    const int*   labels = (const int*)d_in[1];
    float* out = (float*)d_out;

    unsigned short* xnb = (unsigned short*)d_ws;
    unsigned* ap_max = (unsigned*)(xnb + (size_t)NV * DF);
    unsigned* an_min = ap_max + NB;

    const int ntiles = (NB / 16) * (NB / 16 + 1) / 2;   // 2080

    norm_kernel<<<NV / 4, 256, 0, stream>>>(x, xnb, ap_max, an_min);
    dist_kernel<<<ntiles, 256, 0, stream>>>(xnb, labels, ap_max, an_min);
    loss_kernel<<<1, 256, 0, stream>>>(ap_max, an_min, out);
}